// Round 1
// baseline (3940.775 us; speedup 1.0000x reference)
//
#include <hip/hip_runtime.h>
#include <math.h>

#define T_STEPS 50
#define NT 512

// workspace layout (float offsets)
#define WS_FC1T 0          // 1600*256 = 409600  : fc1_w transposed [k][j]
#define WS_W2F  409600     // 32*64*36 = 73728   : folded conv2 [ic][oc][36]
#define WS_W1F  483328     // 36*64    = 2304    : folded conv1 [j][oc*2+ic]
#define WS_TOTAL 485632

// LDS layout (float offsets)
#define L_XT    0          // 2*32*32 = 2048
#define L_SPK1  2048       // 32 planes, stride 228 (14 rows * 16 + pad4) = 7296
#define L_RED   9344       // 8*64*25 = 12800
#define L_W1F   22144      // 2304
#define L_WOUT  24448      // 11*256 = 2816
#define L_SPKFC 27264      // 256
#define L_LIST  27520      // 1600 (ints)
#define L_FLAG  29120      // 448
#define L_PART  29568      // 176
#define L_IPART 29744      // 512
#define L_CNT   30256      // 1 (int)
#define L_TOTALF 30260
#define SMEM_BYTES (L_TOTALF * 4)

__global__ void prep_kernel(const float* __restrict__ conv1_w,
                            const float* __restrict__ conv2_w,
                            const float* __restrict__ fc1_w,
                            float* __restrict__ ws) {
  int i = blockIdx.x * blockDim.x + threadIdx.x;
  if (i < 409600) {
    int k = i >> 8, j = i & 255;
    ws[WS_FC1T + i] = fc1_w[j * 1600 + k];
  } else if (i < 409600 + 73728) {
    int i2 = i - 409600;
    int ic = i2 / 2304, r = i2 % 2304, oc = r / 36, jj = r % 36, u = jj / 6, v = jj % 6;
    float s = 0.f;
    for (int dy = 0; dy < 2; ++dy) {
      int ky = u - dy; if (ky < 0 || ky > 4) continue;
      for (int dx = 0; dx < 2; ++dx) {
        int kx = v - dx; if (kx < 0 || kx > 4) continue;
        s += conv2_w[((oc * 32 + ic) * 5 + ky) * 5 + kx];
      }
    }
    ws[WS_W2F + i2] = 0.25f * s;   // i2 == (ic*64+oc)*36 + jj
  } else if (i < WS_TOTAL) {
    int i3 = i - 483328;
    int jj = i3 >> 6, l = i3 & 63, oc = l >> 1, ic = l & 1, u = jj / 6, v = jj % 6;
    float s = 0.f;
    for (int dy = 0; dy < 2; ++dy) {
      int ky = u - dy; if (ky < 0 || ky > 4) continue;
      for (int dx = 0; dx < 2; ++dx) {
        int kx = v - dx; if (kx < 0 || kx > 4) continue;
        s += conv1_w[((oc * 2 + ic) * 5 + ky) * 5 + kx];
      }
    }
    ws[WS_W1F + i3] = 0.25f * s;   // [jj][l]
  }
}

__global__ __launch_bounds__(NT, 2) void snn_kernel(
    const float* __restrict__ x,
    const float* __restrict__ bn1_gamma, const float* __restrict__ bn1_beta,
    const float* __restrict__ bn1_mean,  const float* __restrict__ bn1_var,
    const float* __restrict__ bn2_gamma, const float* __restrict__ bn2_beta,
    const float* __restrict__ bn2_mean,  const float* __restrict__ bn2_var,
    const float* __restrict__ beta_c1_raw, const float* __restrict__ beta_c2_raw,
    const float* __restrict__ alpha_raw, const float* __restrict__ rho_raw,
    const float* __restrict__ beta_a_p,  const float* __restrict__ fc_out_w,
    const float* __restrict__ beta_out_p,
    const float* __restrict__ ws, float* __restrict__ out)
{
  extern __shared__ float sm[];
  int* listI = (int*)&sm[L_LIST];
  int* cntI  = (int*)&sm[L_CNT];
  const int tid = threadIdx.x, wave = tid >> 6, lane = tid & 63;
  const int b = blockIdx.x;

  // one-time LDS staging
  for (int i = tid; i < 2304; i += NT) sm[L_W1F + i] = ws[WS_W1F + i];
  for (int i = tid; i < 2816; i += NT) sm[L_WOUT + i] = fc_out_w[i];

  // conv1 lane mapping: lane = oc*2 + ic
  const int oc1 = lane >> 1, ic1 = lane & 1;
  const float s1v  = bn1_gamma[oc1] / sqrtf(bn1_var[oc1] + 1e-5f);
  const float sh1v = bn1_beta[oc1] - bn1_mean[oc1] * s1v;
  const float b1v  = 1.f / (1.f + expf(-beta_c1_raw[oc1]));

  int pyBase, npy;
  if (wave < 6) { pyBase = wave * 2; npy = 2; } else { pyBase = 12 + (wave - 6); npy = 1; }

  float v_c1[2][14];
  #pragma unroll
  for (int k = 0; k < 2; ++k)
    #pragma unroll
    for (int p = 0; p < 14; ++p) v_c1[k][p] = 0.f;

  // conv2 finalize mapping: thread t owns n = t + 512k
  float s2r[4], sh2r[4], b2r[4], v_c2[4];
  #pragma unroll
  for (int k = 0; k < 4; ++k) {
    int n = tid + NT * k;
    if (n < 1600) {
      int oc = n / 25;
      float s2 = bn2_gamma[oc] / sqrtf(bn2_var[oc] + 1e-5f);
      s2r[k] = s2; sh2r[k] = bn2_beta[oc] - bn2_mean[oc] * s2;
      b2r[k] = 1.f / (1.f + expf(-beta_c2_raw[oc]));
    } else { s2r[k] = 0.f; sh2r[k] = 0.f; b2r[k] = 0.f; }
    v_c2[k] = 0.f;
  }

  // fc LIF state (owned by tid<256)
  float al = 0.f, rh = 0.f, ba = 0.f, v_fc = 0.f, a_fc = 0.f, spk_prev = 0.f;
  if (tid < 256) {
    al = 1.f / (1.f + expf(-alpha_raw[tid]));
    rh = 1.f / (1.f + expf(-rho_raw[tid]));
    ba = beta_a_p[tid];
  }
  const float beta_o = 1.f / (1.f + expf(-beta_out_p[0]));
  float v_out = 0.f, o_sum = 0.f;  // tid<11

  const float* xbase = x + (size_t)b * T_STEPS * 2048;
  const float* w2f  = ws + WS_W2F;
  const float* fc1T = ws + WS_FC1T;

  __syncthreads();

  for (int t = 0; t < T_STEPS; ++t) {
    // ---- phase 1: stage x_t (512 float4 = 2048 floats) ----
    {
      const float4* src = (const float4*)(xbase + t * 2048);
      ((float4*)&sm[L_XT])[tid] = src[tid];
    }
    __syncthreads();

    // ---- phase 2: conv1 (folded 6x6, stride2) + BN + LIF -> spk1, row flags ----
    {
      float w[36];
      #pragma unroll
      for (int j = 0; j < 36; ++j) w[j] = sm[L_W1F + j * 64 + lane];
      float acc0[14], acc1[14];
      #pragma unroll
      for (int p = 0; p < 14; ++p) { acc0[p] = 0.f; acc1[p] = 0.f; }
      const int iy0 = pyBase * 2;
      const float* xr = &sm[L_XT + ic1 * 1024];
      const int nrows = npy * 2 + 4;
      #pragma unroll
      for (int r = 0; r < 8; ++r) {
        if (r < nrows) {
          float row[32];
          const float4* rp = (const float4*)&xr[(iy0 + r) * 32];
          #pragma unroll
          for (int q = 0; q < 8; ++q) {
            float4 f = rp[q];
            row[4*q] = f.x; row[4*q+1] = f.y; row[4*q+2] = f.z; row[4*q+3] = f.w;
          }
          if (r <= 5) {
            #pragma unroll
            for (int v = 0; v < 6; ++v) {
              float wv = w[r * 6 + v];
              #pragma unroll
              for (int px = 0; px < 14; ++px) acc0[px] += row[2*px + v] * wv;
            }
          }
          if (npy == 2 && r >= 2) {
            #pragma unroll
            for (int v = 0; v < 6; ++v) {
              float wv = w[(r - 2) * 6 + v];
              #pragma unroll
              for (int px = 0; px < 14; ++px) acc1[px] += row[2*px + v] * wv;
            }
          }
        }
      }
      // reduce over ic (lane pairs), BN, LIF
      float flag0 = 0.f, flag1 = 0.f;
      #pragma unroll
      for (int px = 0; px < 14; ++px) {
        float tsum = acc0[px] + __shfl_xor(acc0[px], 1);
        float c = tsum * s1v + sh1v;
        float v = b1v * v_c1[0][px] + (1.f - b1v) * c;
        float s = (v > 1.f) ? 1.f : 0.f;
        v_c1[0][px] = v * (1.f - s);
        acc0[px] = s; flag0 += s;
      }
      if (npy == 2) {
        #pragma unroll
        for (int px = 0; px < 14; ++px) {
          float tsum = acc1[px] + __shfl_xor(acc1[px], 1);
          float c = tsum * s1v + sh1v;
          float v = b1v * v_c1[1][px] + (1.f - b1v) * c;
          float s = (v > 1.f) ? 1.f : 0.f;
          v_c1[1][px] = v * (1.f - s);
          acc1[px] = s; flag1 += s;
        }
      }
      if (ic1 == 0) {
        #pragma unroll
        for (int px = 0; px < 14; ++px) sm[L_SPK1 + oc1 * 228 + pyBase * 16 + px] = acc0[px];
        sm[L_FLAG + oc1 * 14 + pyBase] = flag0;
      } else if (npy == 2) {
        #pragma unroll
        for (int px = 0; px < 14; ++px) sm[L_SPK1 + oc1 * 228 + (pyBase + 1) * 16 + px] = acc1[px];
        sm[L_FLAG + oc1 * 14 + pyBase + 1] = flag1;
      }
      if (tid == 0) *cntI = 0;
    }
    __syncthreads();

    // ---- phase 3: conv2 (folded 6x6, stride2), spike-row-gated; lane=oc, wave covers 4 ic ----
    {
      float acc[25];
      #pragma unroll
      for (int p = 0; p < 25; ++p) acc[p] = 0.f;
      for (int ib = 0; ib < 4; ++ib) {
        const int ic = wave + 8 * ib;
        float w[36];
        {
          const float4* wp = (const float4*)(w2f + (ic * 64 + lane) * 36);
          #pragma unroll
          for (int q = 0; q < 9; ++q) {
            float4 f = wp[q];
            w[4*q] = f.x; w[4*q+1] = f.y; w[4*q+2] = f.z; w[4*q+3] = f.w;
          }
        }
        const float* srow = &sm[L_SPK1 + ic * 228];
        const float* fl = &sm[L_FLAG + ic * 14];
        #pragma unroll
        for (int iy = 0; iy < 14; ++iy) {
          if (fl[iy] != 0.f) {           // wave-uniform branch; exact (row all zero)
            float row[16];
            const float4* rp = (const float4*)&srow[iy * 16];
            #pragma unroll
            for (int q = 0; q < 4; ++q) {
              float4 f = rp[q];
              row[4*q] = f.x; row[4*q+1] = f.y; row[4*q+2] = f.z; row[4*q+3] = f.w;
            }
            #pragma unroll
            for (int py = 0; py < 5; ++py) {
              const int u = iy - 2 * py;
              if (u >= 0 && u <= 5) {
                #pragma unroll
                for (int v = 0; v < 6; ++v) {
                  float wv = w[u * 6 + v];
                  #pragma unroll
                  for (int px = 0; px < 5; ++px) acc[py * 5 + px] += row[2*px + v] * wv;
                }
              }
            }
          }
        }
      }
      #pragma unroll
      for (int p = 0; p < 25; ++p) sm[L_RED + wave * 1600 + lane * 25 + p] = acc[p];
    }
    __syncthreads();

    // ---- phase 4: conv2 cross-wave reduce + BN + LIF -> spike list ----
    {
      #pragma unroll
      for (int k = 0; k < 4; ++k) {
        int n = tid + NT * k;
        if (n < 1600) {
          float ssum = 0.f;
          #pragma unroll
          for (int wv = 0; wv < 8; ++wv) ssum += sm[L_RED + wv * 1600 + n];
          float c2 = ssum * s2r[k] + sh2r[k];
          float v = b2r[k] * v_c2[k] + (1.f - b2r[k]) * c2;
          float s = (v > 1.f) ? 1.f : 0.f;
          v_c2[k] = v * (1.f - s);
          if (s > 0.f) {
            int idx = atomicAdd(cntI, 1);
            listI[idx] = n;
          }
        }
      }
    }
    __syncthreads();

    // ---- phase 5: fc1 = sparse gather of transposed columns ----
    {
      const int j = tid & 255, h = tid >> 8;
      const int nn = *cntI;
      float I = 0.f;
      for (int i = h; i < nn; i += 2) {
        int k = listI[i];
        I += fc1T[k * 256 + j];
      }
      sm[L_IPART + tid] = I;
    }
    __syncthreads();

    // ---- phase 6: adaptive LIF on fc ----
    if (tid < 256) {
      float I = sm[L_IPART + tid] + sm[L_IPART + 256 + tid];
      a_fc = rh * a_fc + (1.f - rh) * spk_prev;
      float v = al * v_fc + (1.f - al) * I;
      float s = (v > 1.f + ba * a_fc) ? 1.f : 0.f;
      v_fc = v * (1.f - s);
      spk_prev = s;
      sm[L_SPKFC + tid] = s;
    }
    __syncthreads();

    // ---- phase 7: fc_out partials (11 outputs x 16 groups) ----
    if (tid < 176) {
      int o = tid >> 4, g = tid & 15;
      float p = 0.f;
      #pragma unroll
      for (int m = 0; m < 16; ++m)
        p += sm[L_SPKFC + g * 16 + m] * sm[L_WOUT + o * 256 + g * 16 + m];
      sm[L_PART + tid] = p;
    }
    __syncthreads();

    // ---- phase 8: output leaky integrator ----
    if (tid < 11) {
      float I = 0.f;
      #pragma unroll
      for (int g = 0; g < 16; ++g) I += sm[L_PART + tid * 16 + g];
      v_out = beta_o * v_out + (1.f - beta_o) * I;
      o_sum += v_out;
    }
    __syncthreads();
  }

  if (tid < 11) out[b * 11 + tid] = o_sum * (1.f / T_STEPS);
}

extern "C" void kernel_launch(void* const* d_in, const int* in_sizes, int n_in,
                              void* d_out, int out_size, void* d_ws, size_t ws_size,
                              hipStream_t stream) {
  const float* x            = (const float*)d_in[0];
  const float* conv1_w      = (const float*)d_in[1];
  const float* bn1_gamma    = (const float*)d_in[2];
  const float* bn1_beta     = (const float*)d_in[3];
  const float* bn1_mean     = (const float*)d_in[4];
  const float* bn1_var      = (const float*)d_in[5];
  const float* conv2_w      = (const float*)d_in[6];
  const float* bn2_gamma    = (const float*)d_in[7];
  const float* bn2_beta     = (const float*)d_in[8];
  const float* bn2_mean     = (const float*)d_in[9];
  const float* bn2_var      = (const float*)d_in[10];
  const float* beta_c1_raw  = (const float*)d_in[11];
  const float* beta_c2_raw  = (const float*)d_in[12];
  const float* fc1_w        = (const float*)d_in[13];
  const float* alpha_raw    = (const float*)d_in[14];
  const float* rho_raw      = (const float*)d_in[15];
  const float* beta_a_p     = (const float*)d_in[16];
  const float* fc_out_w     = (const float*)d_in[17];
  const float* beta_out_p   = (const float*)d_in[18];
  float* ws  = (float*)d_ws;
  float* outp = (float*)d_out;

  (void)in_sizes; (void)n_in; (void)out_size; (void)ws_size;

  hipFuncSetAttribute((const void*)snn_kernel,
                      hipFuncAttributeMaxDynamicSharedMemorySize, SMEM_BYTES);

  prep_kernel<<<dim3((WS_TOTAL + 255) / 256), dim3(256), 0, stream>>>(
      conv1_w, conv2_w, fc1_w, ws);

  snn_kernel<<<dim3(128), dim3(NT), SMEM_BYTES, stream>>>(
      x, bn1_gamma, bn1_beta, bn1_mean, bn1_var,
      bn2_gamma, bn2_beta, bn2_mean, bn2_var,
      beta_c1_raw, beta_c2_raw, alpha_raw, rho_raw, beta_a_p,
      fc_out_w, beta_out_p, ws, outp);
}

// Round 2
// 1054.627 us; speedup vs baseline: 3.7367x; 3.7367x over previous
//
#include <hip/hip_runtime.h>
#include <math.h>

#define T_STEPS 50
#define NT 512

// workspace layout (float offsets)
#define WS_FC1T 0          // 1600*256 = 409600  : fc1_w transposed [k][j]
#define WS_W2F  409600     // 32*64*36 = 73728   : folded conv2 [ic][oc][36]
#define WS_W1F  483328     // 36*64    = 2304    : folded conv1 [j][oc*2+ic]
#define WS_TOTAL 485632

// LDS layout (float offsets)
#define L_XT    0          // 2*32*32 = 2048
#define L_SPK1  2048       // 32 planes, stride 228 (14 rows * 16 + pad4) = 7296
#define L_RED   9344       // 8*64*25 = 12800
#define L_W1F   22144      // 2304
#define L_WOUT  24448      // 11*256 = 2816
#define L_SPKFC 27264      // 256
#define L_LIST  27520      // 1600 (ints)
#define L_FLAG  29120      // 448
#define L_PART  29568      // 176
#define L_IPART 29744      // 512
#define L_CNT   30256      // 1 (int)
#define L_VC1   30260      // 196*32 = 6272 : conv1 membrane, [py*14+px]*32 + oc
#define L_VC2   36532      // 1600          : conv2 membrane
#define L_BN2   38132      // 3*64 = 192    : s2 | sh2 | b2
#define L_TOTALF 38324
#define SMEM_BYTES (L_TOTALF * 4)

__global__ void prep_kernel(const float* __restrict__ conv1_w,
                            const float* __restrict__ conv2_w,
                            const float* __restrict__ fc1_w,
                            float* __restrict__ ws) {
  int i = blockIdx.x * blockDim.x + threadIdx.x;
  if (i < 409600) {
    int k = i >> 8, j = i & 255;
    ws[WS_FC1T + i] = fc1_w[j * 1600 + k];
  } else if (i < 409600 + 73728) {
    int i2 = i - 409600;
    int ic = i2 / 2304, r = i2 % 2304, oc = r / 36, jj = r % 36, u = jj / 6, v = jj % 6;
    float s = 0.f;
    for (int dy = 0; dy < 2; ++dy) {
      int ky = u - dy; if (ky < 0 || ky > 4) continue;
      for (int dx = 0; dx < 2; ++dx) {
        int kx = v - dx; if (kx < 0 || kx > 4) continue;
        s += conv2_w[((oc * 32 + ic) * 5 + ky) * 5 + kx];
      }
    }
    ws[WS_W2F + i2] = 0.25f * s;   // i2 == (ic*64+oc)*36 + jj
  } else if (i < WS_TOTAL) {
    int i3 = i - 483328;
    int jj = i3 >> 6, l = i3 & 63, oc = l >> 1, ic = l & 1, u = jj / 6, v = jj % 6;
    float s = 0.f;
    for (int dy = 0; dy < 2; ++dy) {
      int ky = u - dy; if (ky < 0 || ky > 4) continue;
      for (int dx = 0; dx < 2; ++dx) {
        int kx = v - dx; if (kx < 0 || kx > 4) continue;
        s += conv1_w[((oc * 2 + ic) * 5 + ky) * 5 + kx];
      }
    }
    ws[WS_W1F + i3] = 0.25f * s;   // [jj][l]
  }
}

__global__ __launch_bounds__(NT, 2) void snn_kernel(
    const float* __restrict__ x,
    const float* __restrict__ bn1_gamma, const float* __restrict__ bn1_beta,
    const float* __restrict__ bn1_mean,  const float* __restrict__ bn1_var,
    const float* __restrict__ bn2_gamma, const float* __restrict__ bn2_beta,
    const float* __restrict__ bn2_mean,  const float* __restrict__ bn2_var,
    const float* __restrict__ beta_c1_raw, const float* __restrict__ beta_c2_raw,
    const float* __restrict__ alpha_raw, const float* __restrict__ rho_raw,
    const float* __restrict__ beta_a_p,  const float* __restrict__ fc_out_w,
    const float* __restrict__ beta_out_p,
    const float* __restrict__ ws, float* __restrict__ out)
{
  extern __shared__ float sm[];
  int* listI = (int*)&sm[L_LIST];
  int* cntI  = (int*)&sm[L_CNT];
  const int tid = threadIdx.x, wave = tid >> 6, lane = tid & 63;
  const int b = blockIdx.x;

  // one-time LDS staging + state zero-init
  for (int i = tid; i < 2304; i += NT) sm[L_W1F + i] = ws[WS_W1F + i];
  for (int i = tid; i < 2816; i += NT) sm[L_WOUT + i] = fc_out_w[i];
  for (int i = tid; i < 6272; i += NT) sm[L_VC1 + i] = 0.f;
  for (int i = tid; i < 1600; i += NT) sm[L_VC2 + i] = 0.f;
  if (tid < 64) {
    float s2 = bn2_gamma[tid] / sqrtf(bn2_var[tid] + 1e-5f);
    sm[L_BN2 + tid]       = s2;
    sm[L_BN2 + 64 + tid]  = bn2_beta[tid] - bn2_mean[tid] * s2;
    sm[L_BN2 + 128 + tid] = 1.f / (1.f + expf(-beta_c2_raw[tid]));
  }

  // conv1 lane mapping: lane = oc*2 + ic
  const int oc1 = lane >> 1, ic1 = lane & 1;
  const float s1v  = bn1_gamma[oc1] / sqrtf(bn1_var[oc1] + 1e-5f);
  const float sh1v = bn1_beta[oc1] - bn1_mean[oc1] * s1v;
  const float b1v  = 1.f / (1.f + expf(-beta_c1_raw[oc1]));

  int pyBase, npy;
  if (wave < 6) { pyBase = wave * 2; npy = 2; } else { pyBase = 12 + (wave - 6); npy = 1; }

  // fc LIF state (owned by tid<256)
  float al = 0.f, rh = 0.f, ba = 0.f, v_fc = 0.f, a_fc = 0.f, spk_prev = 0.f;
  if (tid < 256) {
    al = 1.f / (1.f + expf(-alpha_raw[tid]));
    rh = 1.f / (1.f + expf(-rho_raw[tid]));
    ba = beta_a_p[tid];
  }
  const float beta_o = 1.f / (1.f + expf(-beta_out_p[0]));
  float v_out = 0.f, o_sum = 0.f;  // tid<11

  const float* xbase = x + (size_t)b * T_STEPS * 2048;
  const float* w2f  = ws + WS_W2F;
  const float* fc1T = ws + WS_FC1T;

  __syncthreads();

  for (int t = 0; t < T_STEPS; ++t) {
    // ---- phase 1: stage x_t (512 float4 = 2048 floats) ----
    {
      const float4* src = (const float4*)(xbase + t * 2048);
      ((float4*)&sm[L_XT])[tid] = src[tid];
    }
    __syncthreads();

    // ---- phase 2: conv1 (folded 6x6, stride2) + BN + LIF, one output row at a time ----
    {
      float w[36];
      #pragma unroll
      for (int j = 0; j < 36; ++j) w[j] = sm[L_W1F + j * 64 + lane];
      for (int rr = 0; rr < npy; ++rr) {
        const int py = pyBase + rr;
        float acc[14];
        #pragma unroll
        for (int p = 0; p < 14; ++p) acc[p] = 0.f;
        const float* xr = &sm[L_XT + ic1 * 1024 + py * 64];
        #pragma unroll
        for (int r = 0; r < 6; ++r) {
          float row[32];
          const float4* rp = (const float4*)&xr[r * 32];
          #pragma unroll
          for (int q = 0; q < 8; ++q) {
            float4 f = rp[q];
            row[4*q] = f.x; row[4*q+1] = f.y; row[4*q+2] = f.z; row[4*q+3] = f.w;
          }
          #pragma unroll
          for (int v = 0; v < 6; ++v) {
            float wv = w[r * 6 + v];
            #pragma unroll
            for (int px = 0; px < 14; ++px) acc[px] += row[2*px + v] * wv;
          }
        }
        // reduce over ic (lane pairs)
        #pragma unroll
        for (int px = 0; px < 14; ++px) acc[px] += __shfl_xor(acc[px], 1);
        if (ic1 == 0) {
          float flag = 0.f;
          #pragma unroll
          for (int px = 0; px < 14; ++px) {
            float c = acc[px] * s1v + sh1v;
            const int vidx = L_VC1 + (py * 14 + px) * 32 + oc1;
            float vold = sm[vidx];
            float v = b1v * vold + (1.f - b1v) * c;
            float s = (v > 1.f) ? 1.f : 0.f;
            sm[vidx] = v * (1.f - s);
            sm[L_SPK1 + oc1 * 228 + py * 16 + px] = s;
            flag += s;
          }
          sm[L_FLAG + oc1 * 14 + py] = flag;
        }
      }
      if (tid == 0) *cntI = 0;
    }
    __syncthreads();

    // ---- phase 3: conv2 (folded 6x6, stride2), spike-row-gated; lane=oc, wave covers 4 ic ----
    {
      float acc[25];
      #pragma unroll
      for (int p = 0; p < 25; ++p) acc[p] = 0.f;
      for (int ib = 0; ib < 4; ++ib) {
        const int ic = wave + 8 * ib;
        float w[36];
        {
          const float4* wp = (const float4*)(w2f + (ic * 64 + lane) * 36);
          #pragma unroll
          for (int q = 0; q < 9; ++q) {
            float4 f = wp[q];
            w[4*q] = f.x; w[4*q+1] = f.y; w[4*q+2] = f.z; w[4*q+3] = f.w;
          }
        }
        const float* srow = &sm[L_SPK1 + ic * 228];
        const float* fl = &sm[L_FLAG + ic * 14];
        #pragma unroll
        for (int iy = 0; iy < 14; ++iy) {
          if (fl[iy] != 0.f) {           // wave-uniform branch; exact (row all zero)
            float row[16];
            const float4* rp = (const float4*)&srow[iy * 16];
            #pragma unroll
            for (int q = 0; q < 4; ++q) {
              float4 f = rp[q];
              row[4*q] = f.x; row[4*q+1] = f.y; row[4*q+2] = f.z; row[4*q+3] = f.w;
            }
            #pragma unroll
            for (int py = 0; py < 5; ++py) {
              const int u = iy - 2 * py;
              if (u >= 0 && u <= 5) {
                #pragma unroll
                for (int v = 0; v < 6; ++v) {
                  float wv = w[u * 6 + v];
                  #pragma unroll
                  for (int px = 0; px < 5; ++px) acc[py * 5 + px] += row[2*px + v] * wv;
                }
              }
            }
          }
        }
      }
      #pragma unroll
      for (int p = 0; p < 25; ++p) sm[L_RED + wave * 1600 + lane * 25 + p] = acc[p];
    }
    __syncthreads();

    // ---- phase 4: conv2 cross-wave reduce + BN + LIF -> spike list (ballot compaction) ----
    {
      #pragma unroll
      for (int k = 0; k < 4; ++k) {
        int n = tid + NT * k;
        float s = 0.f;
        if (n < 1600) {
          float ssum = 0.f;
          #pragma unroll
          for (int wv = 0; wv < 8; ++wv) ssum += sm[L_RED + wv * 1600 + n];
          int oc = n / 25;
          float c2 = ssum * sm[L_BN2 + oc] + sm[L_BN2 + 64 + oc];
          float b2 = sm[L_BN2 + 128 + oc];
          const int vidx = L_VC2 + n;
          float vold = sm[vidx];
          float v = b2 * vold + (1.f - b2) * c2;
          s = (v > 1.f) ? 1.f : 0.f;
          sm[vidx] = v * (1.f - s);
        }
        unsigned long long mask = __ballot(s > 0.f);
        if (mask) {
          int base = 0;
          if (lane == 0) base = atomicAdd(cntI, __popcll(mask));
          base = __shfl(base, 0);
          if (s > 0.f) {
            int pos = __popcll(mask & ((1ull << lane) - 1ull));
            listI[base + pos] = n;
          }
        }
      }
    }
    __syncthreads();

    // ---- phase 5: fc1 = sparse gather of transposed columns ----
    {
      const int j = tid & 255, h = tid >> 8;
      const int nn = *cntI;
      float I = 0.f;
      for (int i = h; i < nn; i += 2) {
        int k = listI[i];
        I += fc1T[k * 256 + j];
      }
      sm[L_IPART + tid] = I;
    }
    __syncthreads();

    // ---- phase 6: adaptive LIF on fc ----
    if (tid < 256) {
      float I = sm[L_IPART + tid] + sm[L_IPART + 256 + tid];
      a_fc = rh * a_fc + (1.f - rh) * spk_prev;
      float v = al * v_fc + (1.f - al) * I;
      float s = (v > 1.f + ba * a_fc) ? 1.f : 0.f;
      v_fc = v * (1.f - s);
      spk_prev = s;
      sm[L_SPKFC + tid] = s;
    }
    __syncthreads();

    // ---- phase 7: fc_out partials (11 outputs x 16 groups) ----
    if (tid < 176) {
      int o = tid >> 4, g = tid & 15;
      float p = 0.f;
      #pragma unroll
      for (int m = 0; m < 16; ++m)
        p += sm[L_SPKFC + g * 16 + m] * sm[L_WOUT + o * 256 + g * 16 + m];
      sm[L_PART + tid] = p;
    }
    __syncthreads();

    // ---- phase 8: output leaky integrator ----
    if (tid < 11) {
      float I = 0.f;
      #pragma unroll
      for (int g = 0; g < 16; ++g) I += sm[L_PART + tid * 16 + g];
      v_out = beta_o * v_out + (1.f - beta_o) * I;
      o_sum += v_out;
    }
    __syncthreads();
  }

  if (tid < 11) out[b * 11 + tid] = o_sum * (1.f / T_STEPS);
}

extern "C" void kernel_launch(void* const* d_in, const int* in_sizes, int n_in,
                              void* d_out, int out_size, void* d_ws, size_t ws_size,
                              hipStream_t stream) {
  const float* x            = (const float*)d_in[0];
  const float* conv1_w      = (const float*)d_in[1];
  const float* bn1_gamma    = (const float*)d_in[2];
  const float* bn1_beta     = (const float*)d_in[3];
  const float* bn1_mean     = (const float*)d_in[4];
  const float* bn1_var      = (const float*)d_in[5];
  const float* conv2_w      = (const float*)d_in[6];
  const float* bn2_gamma    = (const float*)d_in[7];
  const float* bn2_beta     = (const float*)d_in[8];
  const float* bn2_mean     = (const float*)d_in[9];
  const float* bn2_var      = (const float*)d_in[10];
  const float* beta_c1_raw  = (const float*)d_in[11];
  const float* beta_c2_raw  = (const float*)d_in[12];
  const float* fc1_w        = (const float*)d_in[13];
  const float* alpha_raw    = (const float*)d_in[14];
  const float* rho_raw      = (const float*)d_in[15];
  const float* beta_a_p     = (const float*)d_in[16];
  const float* fc_out_w     = (const float*)d_in[17];
  const float* beta_out_p   = (const float*)d_in[18];
  float* ws  = (float*)d_ws;
  float* outp = (float*)d_out;

  (void)in_sizes; (void)n_in; (void)out_size; (void)ws_size;

  hipFuncSetAttribute((const void*)snn_kernel,
                      hipFuncAttributeMaxDynamicSharedMemorySize, SMEM_BYTES);

  prep_kernel<<<dim3((WS_TOTAL + 255) / 256), dim3(256), 0, stream>>>(
      conv1_w, conv2_w, fc1_w, ws);

  snn_kernel<<<dim3(128), dim3(NT), SMEM_BYTES, stream>>>(
      x, bn1_gamma, bn1_beta, bn1_mean, bn1_var,
      bn2_gamma, bn2_beta, bn2_mean, bn2_var,
      beta_c1_raw, beta_c2_raw, alpha_raw, rho_raw, beta_a_p,
      fc_out_w, beta_out_p, ws, outp);
}